// Round 6
// baseline (35.070 us; speedup 1.0000x reference)
//
#include <hip/hip_runtime.h>
#include <math.h>

#define NATOMS 3000
#define NPAD   3072            // 12 * 256
#define DIM 16
#define NRBF 16
#define CUTOFF 5.0f
#define C2 (CUTOFF * CUTOFF)
#define BOX 45.0f
#define INV_BOX 0.022222223f   // 1.0f/45.0f
#define GAMMA 10.0f
#define NBR_CAP 64
#define NITER (NPAD / 256)     // 12 float4-chunks of 256 atoms
#define NBLOCKS (NATOMS / 4)   // 750

// ws float layout: sx[0,3072) sy[3072,6144) sz[6144,9216) e[9216,12216)
// done-counter (uint) at float offset 12216.

// Transpose AoS xyz -> padded SoA (pads = +INF so dsq = NaN -> pred false)
// and zero the done-counter for this launch. Kernel boundary provides
// cross-XCD visibility of the SoA for the main kernel.
__global__ __launch_bounds__(256) void gnn_prep_kernel(
    const float* __restrict__ xyz, float* __restrict__ ws)
{
    const int j = blockIdx.x * 256 + threadIdx.x;   // 12 blocks -> j < 3072
    float x = INFINITY, y = INFINITY, z = INFINITY;
    if (j < NATOMS) { x = xyz[3 * j]; y = xyz[3 * j + 1]; z = xyz[3 * j + 2]; }
    ws[j] = x; ws[NPAD + j] = y; ws[2 * NPAD + j] = z;
    if (j == 0) ((unsigned int*)(ws + 3 * NPAD + NATOMS))[0] = 0u;
}

// 750 blocks x 4 waves, ONE atom per wave. float4 SoA scan -> ordered ballot
// compaction -> predicated heavy pass -> butterfly reduce -> MLP tail ->
// agent-scope e store; last block to finish reduces all energies (fixed
// order => deterministic) and writes the scalar output.
__global__ __launch_bounds__(256) void gnn_atom_kernel(
    const int* __restrict__ zsp, const float* __restrict__ embed,
    const float* __restrict__ W_rbf, const float* __restrict__ W_msg,
    const float* __restrict__ W1, const float* __restrict__ W2,
    float* __restrict__ ws, float* __restrict__ out)
{
    __shared__ int2 spair[4][NBR_CAP];   // 2 KB: .x = j, .y = dsq bits
    __shared__ float redsh[4];
    __shared__ int slast;

    const int tid  = threadIdx.x;
    const int w    = tid >> 6;
    const int lane = tid & 63;
    const int i    = blockIdx.x * 4 + w;   // 750*4 = 3000 exactly

    float* e = ws + 3 * NPAD;
    unsigned int* ctr = (unsigned int*)(ws + 3 * NPAD + NATOMS);

    const float xi = ws[i];                // SoA self-read (prep done: kernel boundary)
    const float yi = ws[NPAD + i];
    const float zi = ws[2 * NPAD + i];

    const float4* sx4 = (const float4*)(ws);
    const float4* sy4 = (const float4*)(ws + NPAD);
    const float4* sz4 = (const float4*)(ws + 2 * NPAD);

    // --- phase 1: float4 scan + ordered compaction ---
    int cnt = 0;
    const unsigned long long lmask = (1ull << lane) - 1ull;
#pragma unroll 4
    for (int it = 0; it < NITER; ++it) {
        const int v = it * 64 + lane;
        const float4 x4 = sx4[v];
        const float4 y4 = sy4[v];
        const float4 z4 = sz4[v];
        const float xs[4] = {x4.x, x4.y, x4.z, x4.w};
        const float ys[4] = {y4.x, y4.y, y4.z, y4.w};
        const float zs[4] = {z4.x, z4.y, z4.z, z4.w};
#pragma unroll
        for (int q = 0; q < 4; ++q) {
            float dx = xs[q] - xi, dy = ys[q] - yi, dz = zs[q] - zi;
            dx = fmaf(-BOX, rintf(dx * INV_BOX), dx);
            dy = fmaf(-BOX, rintf(dy * INV_BOX), dy);
            dz = fmaf(-BOX, rintf(dz * INV_BOX), dz);
            const float dsq = fmaf(dx, dx, fmaf(dy, dy, dz * dz));
            const bool pred = (dsq < C2) && (dsq > 0.0f);   // NaN pads fail both
            const unsigned long long mask = __ballot(pred);
            if (pred) {
                const int slot = cnt + __popcll(mask & lmask);
                if (slot < NBR_CAP)
                    spair[w][slot] = make_int2(it * 256 + lane * 4 + q,
                                               __float_as_int(dsq));
            }
            cnt += __popcll(mask);
        }
    }
    if (cnt > NBR_CAP) cnt = NBR_CAP;

    // --- phase 2: single predicated heavy pass (<=1 neighbor per lane) ---
    float msg[DIM];
#pragma unroll
    for (int d = 0; d < DIM; ++d) msg[d] = 0.0f;

    if (lane < cnt) {
        const int2 pr = spair[w][lane];
        const float r = sqrtf(__int_as_float(pr.y));
        float rbf[NRBF];
#pragma unroll
        for (int k = 0; k < NRBF; ++k) {
            const float t = r - (float)k * (CUTOFF / 15.0f);
            rbf[k] = __expf(-GAMMA * t * t);
        }
        const float4* hj4 = (const float4*)(embed + (size_t)zsp[pr.x] * DIM);
        const float4 h0 = hj4[0], h1 = hj4[1], h2 = hj4[2], h3 = hj4[3];
        const float hj[DIM] = {h0.x, h0.y, h0.z, h0.w, h1.x, h1.y, h1.z, h1.w,
                               h2.x, h2.y, h2.z, h2.w, h3.x, h3.y, h3.z, h3.w};
#pragma unroll
        for (int d = 0; d < DIM; ++d) {
            float f = 0.0f;
#pragma unroll
            for (int k = 0; k < NRBF; ++k)
                f = fmaf(rbf[k], W_rbf[k * DIM + d], f);   // constant offsets -> s_load
            msg[d] = f * hj[d];
        }
    }

    // --- phase 3: butterfly reduce; every lane ends with total m[d] ---
#pragma unroll
    for (int d = 0; d < DIM; ++d) {
#pragma unroll
        for (int off = 32; off >= 1; off >>= 1)
            msg[d] += __shfl_xor(msg[d], off, 64);
    }

    // --- phase 4: MLP tail on lanes 0-15; agent-scope store of e[i] ---
    if (lane < DIM) {
        float macc = 0.0f;
#pragma unroll
        for (int d = 0; d < DIM; ++d)
            macc = fmaf(msg[d], W_msg[d * DIM + lane], macc);
        const float h = embed[(size_t)zsp[i] * DIM + lane] + tanhf(macc);
        float a1 = 0.0f;
#pragma unroll
        for (int d = 0; d < DIM; ++d)
            a1 = fmaf(__shfl(h, d, 64), W1[d * DIM + lane], a1);
        float t1 = tanhf(a1) * W2[lane];
#pragma unroll
        for (int off = 8; off >= 1; off >>= 1) t1 += __shfl_xor(t1, off, 64);
        if (lane == 0)
            __hip_atomic_store(&e[i], t1, __ATOMIC_RELAXED,
                               __HIP_MEMORY_SCOPE_AGENT);
    }

    // --- phase 5: last-block-done deterministic final reduction ---
    __syncthreads();   // drain all waves' e stores (barrier implies vmcnt(0))
    if (tid == 0) {
        const unsigned int old = __hip_atomic_fetch_add(
            ctr, 1u, __ATOMIC_ACQ_REL, __HIP_MEMORY_SCOPE_AGENT);
        slast = (old == NBLOCKS - 1) ? 1 : 0;
    }
    __syncthreads();
    if (slast) {
        float s = 0.0f;
        for (int k = tid; k < NATOMS; k += 256)
            s += __hip_atomic_load(&e[k], __ATOMIC_RELAXED,
                                   __HIP_MEMORY_SCOPE_AGENT);
        for (int off = 32; off >= 1; off >>= 1) s += __shfl_down(s, off, 64);
        if (lane == 0) redsh[w] = s;
        __syncthreads();
        if (tid == 0) out[0] = redsh[0] + redsh[1] + redsh[2] + redsh[3];
    }
}

extern "C" void kernel_launch(void* const* d_in, const int* in_sizes, int n_in,
                              void* d_out, int out_size, void* d_ws, size_t ws_size,
                              hipStream_t stream) {
    const float* xyz   = (const float*)d_in[0];
    const int*   zsp   = (const int*)d_in[1];
    const float* embed = (const float*)d_in[2];
    const float* W_rbf = (const float*)d_in[3];
    const float* W_msg = (const float*)d_in[4];
    const float* W1    = (const float*)d_in[5];
    const float* W2    = (const float*)d_in[6];
    float* out = (float*)d_out;
    float* ws  = (float*)d_ws;   // 3*NPAD SoA + NATOMS e + counter

    gnn_prep_kernel<<<NPAD / 256, 256, 0, stream>>>(xyz, ws);
    gnn_atom_kernel<<<NBLOCKS, 256, 0, stream>>>(zsp, embed, W_rbf, W_msg,
                                                 W1, W2, ws, out);
}

// Round 8
// 22.909 us; speedup vs baseline: 1.5308x; 1.5308x over previous
//
#include <hip/hip_runtime.h>
#include <math.h>

#define NATOMS 3000
#define NPAD   3072            // 12 * 256
#define DIM 16
#define NRBF 16
#define CUTOFF 5.0f
#define C2 (CUTOFF * CUTOFF)
#define BOX 45.0f
#define INV_BOX 0.022222223f   // 1.0f/45.0f
#define GAMMA 10.0f
#define NBR_CAP 64
#define NITER (NPAD / 256)     // 12 float4-chunks of 256 atoms
#define NBLOCKS (NATOMS / 4)   // 750

// ws float layout: sx[0,3072) sy[3072,6144) sz[6144,9216) p[9216,9966)
// p = per-block partial energies, NaN-canary-initialized each call.

// Transpose AoS xyz -> padded SoA (pads = +INF so dsq = NaN -> pred false)
// and NaN-fill the per-block partial array for this launch.
__global__ __launch_bounds__(256) void gnn_prep_kernel(
    const float* __restrict__ xyz, float* __restrict__ ws)
{
    const int j = blockIdx.x * 256 + threadIdx.x;   // 12 blocks -> j < 3072
    float x = INFINITY, y = INFINITY, z = INFINITY;
    if (j < NATOMS) { x = xyz[3 * j]; y = xyz[3 * j + 1]; z = xyz[3 * j + 2]; }
    ws[j] = x; ws[NPAD + j] = y; ws[2 * NPAD + j] = z;
    if (j < NBLOCKS) ws[3 * NPAD + j] = NAN;        // canary
}

// 750 blocks x 4 waves, ONE atom per wave. float4 SoA scan -> ordered ballot
// compaction -> predicated heavy pass -> butterfly reduce -> MLP tail.
// Each block emits ONE per-block partial (relaxed agent store, distinct
// addresses). Block 0 polls the NaN canaries and reduces all 750 partials
// in fixed order (bitwise-deterministic), writing the scalar output.
__global__ __launch_bounds__(256) void gnn_atom_kernel(
    const int* __restrict__ zsp, const float* __restrict__ embed,
    const float* __restrict__ W_rbf, const float* __restrict__ W_msg,
    const float* __restrict__ W1, const float* __restrict__ W2,
    float* __restrict__ ws, float* __restrict__ out)
{
    __shared__ int2 spair[4][NBR_CAP];   // 2 KB: .x = j, .y = dsq bits
    __shared__ float se[4];
    __shared__ float redsh[4];

    const int tid  = threadIdx.x;
    const int w    = tid >> 6;
    const int lane = tid & 63;
    const int i    = blockIdx.x * 4 + w;   // 750*4 = 3000 exactly

    float* p = ws + 3 * NPAD;              // per-block partials

    const float xi = ws[i];
    const float yi = ws[NPAD + i];
    const float zi = ws[2 * NPAD + i];

    const float4* sx4 = (const float4*)(ws);
    const float4* sy4 = (const float4*)(ws + NPAD);
    const float4* sz4 = (const float4*)(ws + 2 * NPAD);

    // --- phase 1: float4 scan + ordered compaction ---
    int cnt = 0;
    const unsigned long long lmask = (1ull << lane) - 1ull;
#pragma unroll 4
    for (int it = 0; it < NITER; ++it) {
        const int v = it * 64 + lane;
        const float4 x4 = sx4[v];
        const float4 y4 = sy4[v];
        const float4 z4 = sz4[v];
        const float xs[4] = {x4.x, x4.y, x4.z, x4.w};
        const float ys[4] = {y4.x, y4.y, y4.z, y4.w};
        const float zs[4] = {z4.x, z4.y, z4.z, z4.w};
#pragma unroll
        for (int q = 0; q < 4; ++q) {
            float dx = xs[q] - xi, dy = ys[q] - yi, dz = zs[q] - zi;
            dx = fmaf(-BOX, rintf(dx * INV_BOX), dx);
            dy = fmaf(-BOX, rintf(dy * INV_BOX), dy);
            dz = fmaf(-BOX, rintf(dz * INV_BOX), dz);
            const float dsq = fmaf(dx, dx, fmaf(dy, dy, dz * dz));
            const bool pred = (dsq < C2) && (dsq > 0.0f);   // NaN pads fail both
            const unsigned long long mask = __ballot(pred);
            if (pred) {
                const int slot = cnt + __popcll(mask & lmask);
                if (slot < NBR_CAP)
                    spair[w][slot] = make_int2(it * 256 + lane * 4 + q,
                                               __float_as_int(dsq));
            }
            cnt += __popcll(mask);
        }
    }
    if (cnt > NBR_CAP) cnt = NBR_CAP;

    // --- phase 2: single predicated heavy pass (<=1 neighbor per lane) ---
    float msg[DIM];
#pragma unroll
    for (int d = 0; d < DIM; ++d) msg[d] = 0.0f;

    if (lane < cnt) {
        const int2 pr = spair[w][lane];
        const float r = sqrtf(__int_as_float(pr.y));
        float rbf[NRBF];
#pragma unroll
        for (int k = 0; k < NRBF; ++k) {
            const float t = r - (float)k * (CUTOFF / 15.0f);
            rbf[k] = __expf(-GAMMA * t * t);
        }
        const float4* hj4 = (const float4*)(embed + (size_t)zsp[pr.x] * DIM);
        const float4 h0 = hj4[0], h1 = hj4[1], h2 = hj4[2], h3 = hj4[3];
        const float hj[DIM] = {h0.x, h0.y, h0.z, h0.w, h1.x, h1.y, h1.z, h1.w,
                               h2.x, h2.y, h2.z, h2.w, h3.x, h3.y, h3.z, h3.w};
#pragma unroll
        for (int d = 0; d < DIM; ++d) {
            float f = 0.0f;
#pragma unroll
            for (int k = 0; k < NRBF; ++k)
                f = fmaf(rbf[k], W_rbf[k * DIM + d], f);   // constant offsets -> s_load
            msg[d] = f * hj[d];
        }
    }

    // --- phase 3: butterfly reduce; every lane ends with total m[d] ---
#pragma unroll
    for (int d = 0; d < DIM; ++d) {
#pragma unroll
        for (int off = 32; off >= 1; off >>= 1)
            msg[d] += __shfl_xor(msg[d], off, 64);
    }

    // --- phase 4: MLP tail on lanes 0-15 -> per-wave energy in se[w] ---
    if (lane < DIM) {
        float macc = 0.0f;
#pragma unroll
        for (int d = 0; d < DIM; ++d)
            macc = fmaf(msg[d], W_msg[d * DIM + lane], macc);
        const float h = embed[(size_t)zsp[i] * DIM + lane] + tanhf(macc);
        float a1 = 0.0f;
#pragma unroll
        for (int d = 0; d < DIM; ++d)
            a1 = fmaf(__shfl(h, d, 64), W1[d * DIM + lane], a1);
        float t1 = tanhf(a1) * W2[lane];
#pragma unroll
        for (int off = 8; off >= 1; off >>= 1) t1 += __shfl_xor(t1, off, 64);
        if (lane == 0) se[w] = t1;
    }
    __syncthreads();

    // --- phase 5: one relaxed agent store per block (no RMW herd) ---
    if (tid == 0) {
        const float partial = ((se[0] + se[1]) + se[2]) + se[3];
        __hip_atomic_store(&p[blockIdx.x], partial, __ATOMIC_RELAXED,
                           __HIP_MEMORY_SCOPE_AGENT);
    }

    // --- phase 6: block 0 polls canaries, then fixed-order reduction ---
    if (blockIdx.x == 0) {
        const int k0 = tid, k1 = tid + 256, k2 = tid + 512;
        const bool need2 = (k2 < NBLOCKS);              // tid < 238
        float v0, v1, v2 = 0.0f;
        for (;;) {
            v0 = __hip_atomic_load(&p[k0], __ATOMIC_RELAXED,
                                   __HIP_MEMORY_SCOPE_AGENT);
            v1 = __hip_atomic_load(&p[k1], __ATOMIC_RELAXED,
                                   __HIP_MEMORY_SCOPE_AGENT);
            if (need2)
                v2 = __hip_atomic_load(&p[k2], __ATOMIC_RELAXED,
                                       __HIP_MEMORY_SCOPE_AGENT);
            // NaN canary check via self-comparison (v!=v iff NaN)
            const int ok = (v0 == v0) && (v1 == v1) && (!need2 || (v2 == v2));
            if (__syncthreads_and(ok)) break;
            __builtin_amdgcn_s_sleep(2);
        }
        float s = (v0 + v1) + v2;                        // fixed per-thread order
        for (int off = 32; off >= 1; off >>= 1) s += __shfl_down(s, off, 64);
        if (lane == 0) redsh[w] = s;
        __syncthreads();
        if (tid == 0) out[0] = ((redsh[0] + redsh[1]) + redsh[2]) + redsh[3];
    }
}

extern "C" void kernel_launch(void* const* d_in, const int* in_sizes, int n_in,
                              void* d_out, int out_size, void* d_ws, size_t ws_size,
                              hipStream_t stream) {
    const float* xyz   = (const float*)d_in[0];
    const int*   zsp   = (const int*)d_in[1];
    const float* embed = (const float*)d_in[2];
    const float* W_rbf = (const float*)d_in[3];
    const float* W_msg = (const float*)d_in[4];
    const float* W1    = (const float*)d_in[5];
    const float* W2    = (const float*)d_in[6];
    float* out = (float*)d_out;
    float* ws  = (float*)d_ws;   // 3*NPAD SoA + NBLOCKS partials

    gnn_prep_kernel<<<NPAD / 256, 256, 0, stream>>>(xyz, ws);
    gnn_atom_kernel<<<NBLOCKS, 256, 0, stream>>>(zsp, embed, W_rbf, W_msg,
                                                 W1, W2, ws, out);
}